// Round 3
// baseline (451.652 us; speedup 1.0000x reference)
//
#include <hip/hip_runtime.h>

#define H 128
#define W 128
#define RR 32            // output rows per 32-lane group
#define GPI (H / RR)     // row-groups per image = 4

typedef float f32x4 __attribute__((ext_vector_type(4)));

// One 32-lane group handles a 32-row strip of one 128x128 image.
// Each lane owns 4 consecutive x-pixels (f32x4). Rolling input-stationary
// scheme: each input row feeds 5 in-flight output-row accumulators.
// Weight matrix has only 6 distinct values (q=dx^2+dy^2 in {0,1,2,4,5,8})
// and 3 distinct rows (0==4, 1==3): share horizontal sums across acc rows.
__global__ __launch_bounds__(256, 4) void blur5x5_kernel(
        const float* __restrict__ x,
        const float* __restrict__ p_lls,
        float* __restrict__ out,
        int n_groups) {

    // ---- 6 distinct normalized weights ----
    float ils = -1.0f / (2.0f * expf(p_lls[0]));   // -1/(2*ls)
    float u1 = expf(1.0f  * ils);                  // q=1  -> q^2=1
    float u2 = expf(4.0f  * ils);                  // q=2  -> 4
    float u4 = expf(16.0f * ils);                  // q=4  -> 16
    float u5 = expf(25.0f * ils);                  // q=5  -> 25
    float u8 = expf(64.0f * ils);                  // q=8  -> 64
    float inv = 1.0f / (1.0f + 4.0f * (u1 + u2 + u4 + u8) + 8.0f * u5);
    float wa = inv;        // q=0 (center)
    float wb = u1 * inv;   // q=1
    float wc = u2 * inv;   // q=2
    float wd = u4 * inv;   // q=4
    float we = u5 * inv;   // q=5
    float wf = u8 * inv;   // q=8
    // weight rows: r0/r4 = [wf we wd we wf], r1/r3 = [we wc wb wc we],
    //              r2    = [wd wb wa wb wd]

    // ---- group / lane mapping ----
    int gib   = threadIdx.x >> 5;
    int wl    = threadIdx.x & 31;
    int group = blockIdx.x * (blockDim.x >> 5) + gib;
    if (group >= n_groups) return;
    int img = group >> 2;            // / GPI
    int rg  = group & (GPI - 1);
    int r0  = rg * RR;

    const float* ib = x   + (size_t)img * (H * W) + wl * 4;
    float*       ob = out + (size_t)img * (H * W) + wl * 4;

    // acc0 holds the oldest in-flight output row (completed first)
    float acc0[4], acc1[4], acc2[4], acc3[4], acc4[4];
    #pragma unroll
    for (int p = 0; p < 4; ++p) {
        acc0[p] = 0.0f; acc1[p] = 0.0f; acc2[p] = 0.0f;
        acc3[p] = 0.0f; acc4[p] = 0.0f;
    }

    #pragma unroll 4
    for (int i = 0; i < RR + 4; ++i) {      // input rows r0-2 .. r0+RR+1
        int yi = r0 - 2 + i;
        f32x4 v = (f32x4)(0.0f);
        if (yi >= 0 && yi < H)
            v = *reinterpret_cast<const f32x4*>(ib + yi * W);

        // W-halo from neighbor lanes (width-32 sub-wave shuffles)
        float l2 = __shfl_up(v.z, 1, 32);
        float l3 = __shfl_up(v.w, 1, 32);
        float r4 = __shfl_down(v.x, 1, 32);
        float r5 = __shfl_down(v.y, 1, 32);
        if (wl == 0)  { l2 = 0.0f; l3 = 0.0f; }   // left image edge
        if (wl == 31) { r4 = 0.0f; r5 = 0.0f; }   // right image edge
        float e[8] = { l2, l3, v.x, v.y, v.z, v.w, r4, r5 };

        // horizontal sums shared across symmetric weight rows
        #pragma unroll
        for (int p = 0; p < 4; ++p) {
            float sA = e[p]     + e[p + 4];    // cols +-2
            float sB = e[p + 1] + e[p + 3];    // cols +-1
            float c  = e[p + 2];               // center col
            float h0 = fmaf(wf, sA, fmaf(we, sB, wd * c));  // w-rows 0 & 4
            float h1 = fmaf(we, sA, fmaf(wc, sB, wb * c));  // w-rows 1 & 3
            float h2 = fmaf(wd, sA, fmaf(wb, sB, wa * c));  // w-row  2
            // acc_d gets weight row (4-d)
            acc0[p] += h0;
            acc1[p] += h1;
            acc2[p] += h2;
            acc3[p] += h1;
            acc4[p] += h0;
        }

        // out row r0+i-4 is complete
        if (i >= 4) {
            f32x4 o = { acc0[0], acc0[1], acc0[2], acc0[3] };
            __builtin_nontemporal_store(
                o, reinterpret_cast<f32x4*>(ob + (size_t)(r0 + i - 4) * W));
        }

        // shift ring (static indices -> register renaming, no scratch)
        #pragma unroll
        for (int p = 0; p < 4; ++p) {
            acc0[p] = acc1[p]; acc1[p] = acc2[p];
            acc2[p] = acc3[p]; acc3[p] = acc4[p];
            acc4[p] = 0.0f;
        }
    }
}

extern "C" void kernel_launch(void* const* d_in, const int* in_sizes, int n_in,
                              void* d_out, int out_size, void* d_ws, size_t ws_size,
                              hipStream_t stream) {
    (void)n_in; (void)out_size; (void)d_ws; (void)ws_size;
    const float* x   = (const float*)d_in[0];
    const float* lls = (const float*)d_in[1];
    float* out = (float*)d_out;

    int n_img    = in_sizes[0] / (H * W);   // 4096
    int n_groups = n_img * GPI;             // 16384
    int threads  = 256;
    int gpb      = threads / 32;            // 8 groups per block
    int blocks   = (n_groups + gpb - 1) / gpb;

    blur5x5_kernel<<<blocks, threads, 0, stream>>>(x, lls, out, n_groups);
}

// Round 7
// 443.911 us; speedup vs baseline: 1.0174x; 1.0174x over previous
//
#include <hip/hip_runtime.h>

#define H 128
#define W 128
#define RR 32            // output rows per 32-lane group
#define GPI (H / RR)     // row-groups per image = 4

typedef float f32x4 __attribute__((ext_vector_type(4)));

// One 32-lane group handles a 32-row strip of one 128x128 image, lane owns 4
// consecutive x-pixels. Rolling accumulators (5 in-flight output rows) + an
// explicit 4-deep load ring: consume slot k, immediately re-issue row+4 into
// slot k -> the VMEM queue never drains (steady 3-4 loads in flight/wave).
// Weight matrix has 6 distinct values, 3 distinct rows: share horizontal sums.

#define ROW_COMPUTE(vv)                                                     \
    {                                                                       \
        float l2 = __shfl_up((vv).z, 1, 32);                                \
        float l3 = __shfl_up((vv).w, 1, 32);                                \
        float r4 = __shfl_down((vv).x, 1, 32);                              \
        float r5 = __shfl_down((vv).y, 1, 32);                              \
        if (wl == 0)  { l2 = 0.0f; l3 = 0.0f; }                             \
        if (wl == 31) { r4 = 0.0f; r5 = 0.0f; }                             \
        float eArr[8] = { l2, l3, (vv).x, (vv).y, (vv).z, (vv).w, r4, r5 }; \
        _Pragma("unroll")                                                   \
        for (int p = 0; p < 4; ++p) {                                       \
            float sA = eArr[p]     + eArr[p + 4];                           \
            float sB = eArr[p + 1] + eArr[p + 3];                           \
            float c  = eArr[p + 2];                                         \
            float h0 = fmaf(wf, sA, fmaf(we, sB, wd * c));                  \
            float h1 = fmaf(we, sA, fmaf(wc, sB, wb * c));                  \
            float h2 = fmaf(wd, sA, fmaf(wb, sB, wa * c));                  \
            acc[0][p] += h0; acc[1][p] += h1; acc[2][p] += h2;              \
            acc[3][p] += h1; acc[4][p] += h0;                               \
        }                                                                   \
    }

#define ACC_SHIFT                                                           \
    _Pragma("unroll")                                                       \
    for (int d = 0; d < 4; ++d) {                                           \
        _Pragma("unroll")                                                   \
        for (int p = 0; p < 4; ++p) acc[d][p] = acc[d + 1][p];              \
    }                                                                       \
    _Pragma("unroll")                                                       \
    for (int p = 0; p < 4; ++p) acc[4][p] = 0.0f;

#define STORE_ROW(orow)                                                     \
    {                                                                       \
        f32x4 o = { acc[0][0], acc[0][1], acc[0][2], acc[0][3] };           \
        __builtin_nontemporal_store(o,                                      \
            reinterpret_cast<f32x4*>(ob + (size_t)(orow) * W));             \
    }

__global__ __launch_bounds__(256, 4) void blur5x5_kernel(
        const float* __restrict__ x,
        const float* __restrict__ p_lls,
        float* __restrict__ out,
        int n_groups) {

    // ---- 6 distinct normalized weights (q = dx^2+dy^2 in {0,1,2,4,5,8}) ----
    float ils = -1.0f / (2.0f * expf(p_lls[0]));
    float u1 = expf(ils);
    float u2 = expf(4.0f  * ils);
    float u4 = expf(16.0f * ils);
    float u5 = expf(25.0f * ils);
    float u8 = expf(64.0f * ils);
    float inv = 1.0f / (1.0f + 4.0f * (u1 + u2 + u4 + u8) + 8.0f * u5);
    const float wa = inv,      wb = u1 * inv, wc = u2 * inv,
                wd = u4 * inv, we = u5 * inv, wf = u8 * inv;

    // ---- group / lane mapping ----
    const int gib   = threadIdx.x >> 5;
    const int wl    = threadIdx.x & 31;
    const int group = blockIdx.x * (blockDim.x >> 5) + gib;
    if (group >= n_groups) return;
    const int img = group >> 2;            // / GPI
    const int rg  = group & (GPI - 1);
    const int r0  = rg * RR;

    const float* ib = x   + (size_t)img * (H * W) + wl * 4;
    float*       ob = out + (size_t)img * (H * W) + wl * 4;

    float acc[5][4];
    #pragma unroll
    for (int d = 0; d < 5; ++d) {
        #pragma unroll
        for (int p = 0; p < 4; ++p) acc[d][p] = 0.0f;
    }

    f32x4 ring[4];   // statically indexed everywhere (k is literal)

    // prologue: issue loads for input rows 0..3 (yi = r0-2 .. r0+1)
    #pragma unroll
    for (int k = 0; k < 4; ++k) {
        const int yi = r0 - 2 + k;
        f32x4 v = (f32x4)(0.0f);
        if (yi >= 0 && yi < H)
            v = *reinterpret_cast<const f32x4*>(ib + yi * W);
        ring[k] = v;
    }

    // m = 0: consume rows 0..3, prefetch rows 4..7, no stores yet
    #pragma unroll
    for (int k = 0; k < 4; ++k) {
        f32x4 v = ring[k];
        {
            const int yn = r0 + 2 + k;         // yi of input row k+4 (>= 2)
            f32x4 nv = (f32x4)(0.0f);
            if (yn < H) nv = *reinterpret_cast<const f32x4*>(ib + yn * W);
            ring[k] = nv;
        }
        ROW_COMPUTE(v);
        ACC_SHIFT;
    }

    // steady state: consume row i = 4m+k, prefetch row i+4, store row i-4
    for (int m = 1; m < 8; ++m) {
        #pragma unroll
        for (int k = 0; k < 4; ++k) {
            const int i = 4 * m + k;
            f32x4 v = ring[k];
            {
                const int yn = r0 + 2 + i;     // yi of input row i+4 (>= 6)
                f32x4 nv = (f32x4)(0.0f);
                if (yn < H) nv = *reinterpret_cast<const f32x4*>(ib + yn * W);
                ring[k] = nv;
            }
            ROW_COMPUTE(v);
            STORE_ROW(r0 + i - 4);
            ACC_SHIFT;
        }
    }

    // epilogue: consume rows 32..35, store out rows 28..31, no loads
    #pragma unroll
    for (int k = 0; k < 4; ++k) {
        const int i = 32 + k;
        f32x4 v = ring[k];
        ROW_COMPUTE(v);
        STORE_ROW(r0 + i - 4);
        ACC_SHIFT;
    }
}

extern "C" void kernel_launch(void* const* d_in, const int* in_sizes, int n_in,
                              void* d_out, int out_size, void* d_ws, size_t ws_size,
                              hipStream_t stream) {
    (void)n_in; (void)out_size; (void)d_ws; (void)ws_size;
    const float* x   = (const float*)d_in[0];
    const float* lls = (const float*)d_in[1];
    float* out = (float*)d_out;

    int n_img    = in_sizes[0] / (H * W);   // 4096
    int n_groups = n_img * GPI;             // 16384
    int threads  = 256;
    int gpb      = threads / 32;            // 8 groups per block
    int blocks   = (n_groups + gpb - 1) / gpb;

    blur5x5_kernel<<<blocks, threads, 0, stream>>>(x, lls, out, n_groups);
}